// Round 9
// baseline (54.352 us; speedup 1.0000x reference)
//
#include <hip/hip_runtime.h>
#include <hip/hip_fp16.h>

// WideModel: 8 hashed multi-hot features + sparse linear combine.
// Strategy R8: FEATURE <-> XCD AFFINITY. Blocks round-robin across the 8
// XCDs, so feature = blockIdx & 7 pins each feature's weight table to ONE
// XCD's private 4MB L2: f0..f5 = 400KB fp32, s0/s1 = 2MB fp16 (pre-pass
// conversion into d_ws). Scattered W-gathers then hit XCD-local L2 instead
// of thrashing 10.4MB of tables through every XCD.
// Dedupe: R5's proven write-winner LDS idiom (plain volatile stores, no
// atomics, no sort). One wave per (row, feature); bias-init + atomicAdd.

constexpr int B = 16384;
constexpr int L = 50;
constexpr int SLOTS = 128;
constexpr int SSZ = 1000000;

struct KArgs {
    const int*    x[8];
    const float*  wf[6];   // f0..f5 fp32 tables (unconverted)
    const __half* ws0;     // s0 fp16 table in d_ws
    const __half* ws1;     // s1 fp16 table in d_ws
    float*        out;
};

// ---- pre-pass: s0,s1 fp32 -> fp16 into d_ws (4 MB total) ----
__global__ __launch_bounds__(256) void conv_s_kernel(const float* __restrict__ s0,
                                                     const float* __restrict__ s1,
                                                     __half* __restrict__ dst) {
    const int e = (blockIdx.x * 256 + (int)threadIdx.x) * 4;
    if (e >= 2 * SSZ) return;
    const float* src = (e < SSZ) ? s0 : s1;
    const int idx    = (e < SSZ) ? e  : e - SSZ;       // SSZ % 4 == 0
    const float4 v = reinterpret_cast<const float4*>(src)[idx >> 2];
    *reinterpret_cast<__half2*>(dst + e)     = __floats2half2_rn(v.x, v.y);
    *reinterpret_cast<__half2*>(dst + e + 2) = __floats2half2_rn(v.z, v.w);
}

__global__ __launch_bounds__(256) void init_kernel(float* out, const float* bias) {
    const int i = blockIdx.x * 256 + (int)threadIdx.x;
    out[i] = bias[0];
}

// ---- main: wave per (row, feature); feature = blockIdx & 7 ----
__global__ __launch_bounds__(256) void wide_xcd_kernel(KArgs a) {
    __shared__ unsigned tbl[4][SLOTS];               // 2 KB/block, wave-private

    const int wave = threadIdx.x >> 6;
    const int lane = threadIdx.x & 63;
    const int feat = (int)(blockIdx.x & 7u);         // pins feature to XCD
    const int row  = (int)((blockIdx.x >> 3) * 4) + wave;

    // coalesced input load; nontemporal: don't evict table lines from L2
    int v = -1;
    if (lane < L) v = __builtin_nontemporal_load(a.x[feat] + row * L + lane);
    const bool valid = (v >= 0);

    // wave-uniform runtime bucket select (scalar branch, both magic-muls cheap)
    const unsigned bin = (feat < 6) ? ((unsigned)v % 100000u)
                                    : ((unsigned)v % 1000000u);

    // write-winner dedupe (R5): plain volatile stores, HW picks one winner
    volatile unsigned* t = tbl[wave];
    t[lane]      = 0xFFFFFFFFu;                      // clear (packed < 2^26)
    t[lane + 64] = 0xFFFFFFFFu;
    // same-wave LDS ops are processed in order; no barrier needed

    const unsigned packed = (bin << 6) | (unsigned)lane;
    unsigned h = (bin * 2654435761u) >> 25;          // top 7 bits -> [0,128)
    bool pend = valid, keep = false;

    while (__any(pend)) {
        if (pend) {
            t[h] = packed;                           // one deterministic winner
            const unsigned r = t[h];
            if ((r >> 6) == bin) {                   // our bin owns the slot
                keep = (r == packed);                // exactly one keeper/bin
                pend = false;
            } else {
                h = (h + 1) & (SLOTS - 1);           // foreign bin: probe on
            }
        }
    }

    // gather from the XCD-local table
    float acc = 0.0f;
    if (keep) {
        if (feat < 6) acc = a.wf[feat][bin];
        else          acc = __half2float((feat == 6 ? a.ws0 : a.ws1)[bin]);
    }

    // wave sum + one atomic per (row, feature)
    #pragma unroll
    for (int off = 32; off; off >>= 1)
        acc += __shfl_xor(acc, off, 64);

    if (lane == 0) atomicAdd(&a.out[row], acc);
}

extern "C" void kernel_launch(void* const* d_in, const int* in_sizes, int n_in,
                              void* d_out, int out_size, void* d_ws, size_t ws_size,
                              hipStream_t stream) {
    __half* wbase = (__half*)d_ws;

    conv_s_kernel<<<(2 * SSZ / 4 + 255) / 256, 256, 0, stream>>>(
        (const float*)d_in[14], (const float*)d_in[15], wbase);

    init_kernel<<<B / 256, 256, 0, stream>>>((float*)d_out,
                                             (const float*)d_in[16]);

    KArgs a;
    for (int i = 0; i < 8; ++i) a.x[i]  = (const int*)d_in[i];
    for (int i = 0; i < 6; ++i) a.wf[i] = (const float*)d_in[8 + i];
    a.ws0 = wbase;
    a.ws1 = wbase + SSZ;
    a.out = (float*)d_out;

    // 8 features x 4096 blocks (4 rows/block); feature = blockIdx & 7
    wide_xcd_kernel<<<8 * (B / 4), 256, 0, stream>>>(a);
}

// Round 10
// 45.022 us; speedup vs baseline: 1.2072x; 1.2072x over previous
//
#include <hip/hip_runtime.h>
#include <hip/hip_fp16.h>

// WideModel R9: feature<->XCD affinity (feat = blockIdx&7 pins each weight
// table to one XCD's L2; s0/s1 pre-converted to fp16 in d_ws) + per-wave
// overhead amortized over G=8 rows per wave (16384 waves total).
// Dedupe: write-winner LDS idiom, UNCONDITIONAL writes (no exec juggling):
//  - invalid lanes use sentinel bin 0x1FFFFF (> any real bin) and resolve as
//    a normal group; their gather is predicated off by `valid`.
//  - done lanes keep rewriting their OWNED slot (same bin bits) - readers
//    only compare bin bits, so this never corrupts; a pending group whose
//    write wins a contended slot claims it; probes strictly shorten.
//  - 3 straight-line rounds + rarely-entered straggler loop.

constexpr int B = 16384;
constexpr int L = 50;
constexpr int G = 8;            // rows per wave
constexpr int SLOTS = 128;
constexpr int SSZ = 1000000;

struct KArgs {
    const int*    x[8];
    const float*  wf[6];
    const __half* ws0;
    const __half* ws1;
    const float*  bias;
    float*        out;
};

__global__ __launch_bounds__(256) void conv_s_kernel(const float* __restrict__ s0,
                                                     const float* __restrict__ s1,
                                                     __half* __restrict__ dst) {
    const int e = (blockIdx.x * 256 + (int)threadIdx.x) * 4;
    if (e >= 2 * SSZ) return;
    const float* src = (e < SSZ) ? s0 : s1;
    const int idx    = (e < SSZ) ? e  : e - SSZ;
    const float4 v = reinterpret_cast<const float4*>(src)[idx >> 2];
    *reinterpret_cast<__half2*>(dst + e)     = __floats2half2_rn(v.x, v.y);
    *reinterpret_cast<__half2*>(dst + e + 2) = __floats2half2_rn(v.z, v.w);
}

__global__ __launch_bounds__(256) void init_kernel(float* out, const float* bias) {
    const int i = blockIdx.x * 256 + (int)threadIdx.x;
    out[i] = bias[0];
}

template <unsigned BUCKET, typename TW>
__device__ __forceinline__ void feat_rows(const int* __restrict__ xbase,
                                          const TW* __restrict__ W,
                                          float* __restrict__ out, int row0,
                                          volatile unsigned* t, int lane) {
    // all G row-loads issued up front (coalesced 200 B segments)
    int v[G];
    #pragma unroll
    for (int g = 0; g < G; ++g)
        v[g] = (lane < L)
             ? __builtin_nontemporal_load(xbase + (row0 + g) * L + lane)
             : -1;

    #pragma unroll
    for (int g = 0; g < G; ++g) {
        const bool valid = (v[g] >= 0);
        unsigned bin = (unsigned)v[g] % BUCKET;
        bin = valid ? bin : 0x1FFFFFu;               // sentinel group for pads
        const unsigned packed = (bin << 6) | (unsigned)lane;
        unsigned h = (bin * 2654435761u) >> 25;      // [0,128)

        // clear (in-order LDS: next writes can't overtake)
        t[lane]      = 0xFFFFFFFFu;
        t[lane + 64] = 0xFFFFFFFFu;

        bool done = false, keep = false;

        // 3 straight-line rounds, all lanes unconditionally
        #pragma unroll
        for (int r = 0; r < 3; ++r) {
            t[h] = packed;
            const unsigned rd = t[h];
            const bool own = ((rd >> 6) == bin);
            keep |= (!done) & (rd == packed);
            done |= own;
            h = done ? h : ((h + 1) & (SLOTS - 1));
        }

        // rare stragglers (long probe chains)
        while (__any(!done)) {
            if (!done) {
                t[h] = packed;
                const unsigned rd = t[h];
                const bool own = ((rd >> 6) == bin);
                keep |= (rd == packed);
                done |= own;
                h = done ? h : ((h + 1) & (SLOTS - 1));
            }
        }

        // predicated gather (XCD-local table), wave reduce, one atomic
        float acc = 0.0f;
        if (keep & valid) acc = (float)W[bin];

        #pragma unroll
        for (int off = 32; off; off >>= 1)
            acc += __shfl_xor(acc, off, 64);

        if (lane == 0) atomicAdd(&out[row0 + g], acc);
    }
}

__global__ __launch_bounds__(256) void wide_r9_kernel(KArgs a) {
    __shared__ unsigned tbl[4][SLOTS];               // 2 KB/block, wave-private

    const int wave = threadIdx.x >> 6;
    const int lane = threadIdx.x & 63;
    const int feat = (int)(blockIdx.x & 7u);         // pins feature to XCD
    const int row0 = (int)(blockIdx.x >> 3) * (4 * G) + wave * G;

    volatile unsigned* t = tbl[wave];

    if (feat < 6)
        feat_rows<100000u, float>(a.x[feat], a.wf[feat], a.out, row0, t, lane);
    else if (feat == 6)
        feat_rows<1000000u, __half>(a.x[6], a.ws0, a.out, row0, t, lane);
    else
        feat_rows<1000000u, __half>(a.x[7], a.ws1, a.out, row0, t, lane);
}

extern "C" void kernel_launch(void* const* d_in, const int* in_sizes, int n_in,
                              void* d_out, int out_size, void* d_ws, size_t ws_size,
                              hipStream_t stream) {
    __half* wbase = (__half*)d_ws;

    conv_s_kernel<<<(2 * SSZ / 4 + 255) / 256, 256, 0, stream>>>(
        (const float*)d_in[14], (const float*)d_in[15], wbase);

    init_kernel<<<B / 256, 256, 0, stream>>>((float*)d_out,
                                             (const float*)d_in[16]);

    KArgs a;
    for (int i = 0; i < 8; ++i) a.x[i]  = (const int*)d_in[i];
    for (int i = 0; i < 6; ++i) a.wf[i] = (const float*)d_in[8 + i];
    a.ws0  = wbase;
    a.ws1  = wbase + SSZ;
    a.bias = (const float*)d_in[16];
    a.out  = (float*)d_out;

    // 8 features x 512 blocks; 4 waves x 8 rows per block
    wide_r9_kernel<<<8 * (B / (4 * G)), 256, 0, stream>>>(a);
}

// Round 11
// 39.821 us; speedup vs baseline: 1.3649x; 1.1306x over previous
//
#include <hip/hip_runtime.h>

// WideModel R10: R5's write-winner structure + maximum concurrency.
//  - __launch_bounds__(256,8): allow 8 blocks/CU = 32 waves/CU resident
//  - features processed in PAIRS on ping-pong tables A/B: both round-0
//    write+read issued back-to-back, ONE straggler loop per pair
//    (convergence points and serial LDS round-trips halved vs R5)
//  - deferred gathers: W-load issued immediately after each pair resolves,
//    held in per-feature registers, vmcnt drained only at the final sum
//    (up to 8 scattered loads in flight per wave)
//  - single kernel, fp32 tables, one plain store per row

constexpr int B = 16384;
constexpr int L = 50;
constexpr int SLOTS = 128;

struct KArgs {
    const int*   x[8];
    const float* w[8];
    const float* bias;
    float*       out;
};

__global__ __launch_bounds__(256, 8) void wide_pp_kernel(KArgs a) {
    __shared__ unsigned tbl[4][2][SLOTS];        // 4 waves x {A,B} x 128 = 4 KB

    const int wave = threadIdx.x >> 6;
    const int lane = threadIdx.x & 63;
    const int row  = (blockIdx.x << 2) | wave;

    // ---- all 8 feature rows in flight up front (coalesced 200 B each) ----
    int v[8];
    #pragma unroll
    for (int f = 0; f < 8; ++f)
        v[f] = (lane < L) ? a.x[f][row * L + lane] : -1;

    // ---- hash all 8 (compile-time magic-mul mod) ----
    unsigned bin[8], pk[8], h0[8];
    bool valid[8];
    #pragma unroll
    for (int f = 0; f < 8; ++f) {
        valid[f] = (v[f] >= 0);
        bin[f] = (f < 6) ? ((unsigned)v[f] % 100000u)
                         : ((unsigned)v[f] % 1000000u);
        pk[f]  = (bin[f] << 6) | (unsigned)lane;
        h0[f]  = (bin[f] * 2654435761u) >> 25;   // top 7 bits -> [0,128)
    }

    volatile unsigned* tA = tbl[wave][0];
    volatile unsigned* tB = tbl[wave][1];

    float wv[8];

    // ---- 4 pairs, ping-pong tables ----
    #pragma unroll
    for (int p = 0; p < 4; ++p) {
        const int fA = 2 * p, fB = 2 * p + 1;

        // clear both tables (packed < 2^26 never matches ~0)
        tA[lane] = 0xFFFFFFFFu; tA[lane + 64] = 0xFFFFFFFFu;
        tB[lane] = 0xFFFFFFFFu; tB[lane + 64] = 0xFFFFFFFFu;
        // same-wave LDS ops process in order; no barrier needed

        unsigned hA = h0[fA], hB = h0[fB];
        bool pA = valid[fA], pB = valid[fB], kA = false, kB = false;

        // round 0: both features back-to-back (overlapped LDS round-trips)
        if (pA) tA[hA] = pk[fA];
        if (pB) tB[hB] = pk[fB];
        const unsigned rA = pA ? tA[hA] : 0u;
        const unsigned rB = pB ? tB[hB] : 0u;

        if (pA) {
            if ((rA >> 6) == bin[fA]) { kA = (rA == pk[fA]); pA = false; }
            else                        hA = (hA + 1) & (SLOTS - 1);
        }
        if (pB) {
            if ((rB >> 6) == bin[fB]) { kB = (rB == pk[fB]); pB = false; }
            else                        hB = (hB + 1) & (SLOTS - 1);
        }

        // one shared straggler loop per pair (rare)
        while (__any(pA || pB)) {
            if (pA) {
                tA[hA] = pk[fA];
                const unsigned r = tA[hA];
                if ((r >> 6) == bin[fA]) { kA = (r == pk[fA]); pA = false; }
                else                       hA = (hA + 1) & (SLOTS - 1);
            }
            if (pB) {
                tB[hB] = pk[fB];
                const unsigned r = tB[hB];
                if ((r >> 6) == bin[fB]) { kB = (r == pk[fB]); pB = false; }
                else                       hB = (hB + 1) & (SLOTS - 1);
            }
        }

        // deferred gathers: issue now, consume at the very end
        wv[fA] = kA ? a.w[fA][bin[fA]] : 0.0f;
        wv[fB] = kB ? a.w[fB][bin[fB]] : 0.0f;
    }

    // ---- drain all gathers, reduce, store ----
    float acc = 0.0f;
    #pragma unroll
    for (int f = 0; f < 8; ++f) acc += wv[f];

    #pragma unroll
    for (int off = 32; off; off >>= 1)
        acc += __shfl_xor(acc, off, 64);

    if (lane == 0) a.out[row] = acc + a.bias[0];
}

extern "C" void kernel_launch(void* const* d_in, const int* in_sizes, int n_in,
                              void* d_out, int out_size, void* d_ws, size_t ws_size,
                              hipStream_t stream) {
    KArgs a;
    for (int i = 0; i < 8; ++i) a.x[i] = (const int*)d_in[i];
    for (int i = 0; i < 8; ++i) a.w[i] = (const float*)d_in[8 + i];
    a.bias = (const float*)d_in[16];
    a.out  = (float*)d_out;

    wide_pp_kernel<<<B / 4, 256, 0, stream>>>(a);
}